// Round 6
// baseline (1644.751 us; speedup 1.0000x reference)
//
#include <hip/hip_runtime.h>
#include <math.h>
#include <stdint.h>

#define SEQ    512
#define BATCH  64
#define IN_    64
#define HID    512
#define MID    256
#define CONCAT 1088
#define ZS     320
#define NW     4      // workgroups per batch
#define QZ     64     // MID/NW: z_mid rows per WG

typedef _Float16 h2t __attribute__((ext_vector_type(2)));

__device__ __forceinline__ float fdot2u(uint32_t a, uint32_t b, float c) {
    return __builtin_amdgcn_fdot2(__builtin_bit_cast(h2t, a),
                                  __builtin_bit_cast(h2t, b), c, false);
}
__device__ __forceinline__ uint32_t packrtn(float a, float b) {
    h2t h = { (_Float16)a, (_Float16)b };
    return __builtin_bit_cast(uint32_t, h);
}
template <int CTRL>
__device__ __forceinline__ float dpp_add(float v) {
    int o = __builtin_amdgcn_update_dpp(0, __builtin_bit_cast(int, v), CTRL, 0xF, 0xF, true);
    return v + __builtin_bit_cast(float, o);
}
template <int CTRL>
__device__ __forceinline__ float dpp_get(float v) {   // fetch lane-permuted value
    int o = __builtin_amdgcn_update_dpp(0, __builtin_bit_cast(int, v), CTRL, 0xF, 0xF, true);
    return __builtin_bit_cast(float, o);
}
__device__ __forceinline__ float red16(float v) {     // sum over 16-lane group
    v = dpp_add<0xB1>(v);   // quad_perm xor1
    v = dpp_add<0x4E>(v);   // quad_perm xor2
    v = dpp_add<0x124>(v);  // row_ror:4
    v = dpp_add<0x128>(v);  // row_ror:8
    return v;
}
// zin: 16 chunks x 34 u32, padded to 36 (16B-aligned chunk base)
__device__ __forceinline__ int zidx(int k) { return (k / 34) * 36 + (k % 34); }

// Stamped exchange buffer: [BATCH][2(parity)][NW][HID] u64 words.
// hi32 = step stamp (t+1), lo32 = packed fp16 (s-partial, m-partial).
// Atomic 8B word => data self-validating; relaxed atomics suffice. Never
// reset: first call sees zero stamps; replays may read the previous replay's
// final-step word, which is bit-identical (kernel is deterministic).
__device__ uint64_t g_px[(size_t)BATCH * 2 * NW * HID];

// 4 WGs per batch. WG w holds: W_z rows [64w,64w+64) (full K=1088), and
// W_s/W_m COLUMN slices {x cols 16w..16w+15} U {z cols 64+64w..64+64w+63}
// for ALL 512 rows (1 thread per h row -> no reduce). One stamped-word LLC
// exchange per step (3 peer loads issued concurrently); state finishing is
// redundant in all 4 WGs. Double-buffered LDS staging -> 2 barriers/step.
__global__ __launch_bounds__(512, 1)
void metamu7_kernel(const float* __restrict__ x,      // [SEQ][BATCH][IN_]
                    const float* __restrict__ old_m,  // [BATCH][HID]
                    const float* __restrict__ old_s,  // [BATCH][HID]
                    const float* __restrict__ W_z,    // [MID][CONCAT]
                    const float* __restrict__ b_z,
                    const float* __restrict__ W_s,    // [HID][ZS]
                    const float* __restrict__ b_s,
                    const float* __restrict__ W_m,    // [HID][ZS]
                    const float* __restrict__ b_m,
                    float* __restrict__ out)
{
    const int bid = blockIdx.x;
    const int b   = bid & 63;      // batch
    const int w   = bid >> 6;      // quarter
    const int tid = threadIdx.x;
    const int h   = tid;           // phase-B / finish row (global h)

    __shared__ __align__(16) uint32_t zin2[2][16 * 36]; // [x|m|1/s] fp16 pairs
    __shared__ __align__(16) uint32_t zvec2[2][40];     // [x-slice(8)|z-quarter(32)]

    const int g = tid >> 4, c = tid & 15;               // phase A: row pair, K-chunk

    // ---- one-time: weights -> VGPRs (fp16 RTN) ----
    uint32_t wA0[34], wA1[34];
    {
        const float* p0 = W_z + (size_t)(QZ * w + 2 * g) * CONCAT + 68 * c;
        const float* p1 = p0 + CONCAT;
        #pragma unroll
        for (int i = 0; i < 34; ++i) {
            float2 a  = *reinterpret_cast<const float2*>(p0 + 2 * i);
            float2 bb = *reinterpret_cast<const float2*>(p1 + 2 * i);
            wA0[i] = packrtn(a.x, a.y);
            wA1[i] = packrtn(bb.x, bb.y);
        }
    }
    uint32_t wS[40], wM[40];
    {
        const float* ps = W_s + (size_t)h * ZS;
        const float* pm = W_m + (size_t)h * ZS;
        #pragma unroll
        for (int i = 0; i < 8; ++i) {   // x-col slice: cols 16w+2i
            float2 a  = *reinterpret_cast<const float2*>(ps + 16 * w + 2 * i);
            float2 bb = *reinterpret_cast<const float2*>(pm + 16 * w + 2 * i);
            wS[i] = packrtn(a.x, a.y);
            wM[i] = packrtn(bb.x, bb.y);
        }
        #pragma unroll
        for (int i = 0; i < 32; ++i) {  // z-col slice: cols 64+64w+2i
            float2 a  = *reinterpret_cast<const float2*>(ps + 64 + 64 * w + 2 * i);
            float2 bb = *reinterpret_cast<const float2*>(pm + 64 + 64 * w + 2 * i);
            wS[8 + i] = packrtn(a.x, a.y);
            wM[8 + i] = packrtn(bb.x, bb.y);
        }
    }
    const float bz0 = b_z[QZ * w + 2 * g], bz1 = b_z[QZ * w + 2 * g + 1];
    const float bsv = b_s[h], bmv = b_m[h];

    // ---- registers: full per-h state (redundant across the 4 WGs) ----
    float sreg = old_s[b * HID + h];
    float mreg = old_m[b * HID + h];

    // x prefetch: threads 0..31 hold float pair (2*tid, 2*tid+1)
    float2 xv = {0.f, 0.f};
    if (tid < 32) xv = *reinterpret_cast<const float2*>(x + (size_t)b * IN_ + 2 * tid);

    // ---- initial staging of zin[0](t=0) and zvec[0] x-slice ----
    if (tid < 256) {
        float2 mv = *reinterpret_cast<const float2*>(old_m + b * HID + 2 * tid);
        zin2[0][zidx(32 + tid)] = packrtn(mv.x, mv.y);
    } else {
        const int j = tid - 256;
        float2 sv = *reinterpret_cast<const float2*>(old_s + b * HID + 2 * j);
        zin2[0][zidx(288 + j)] = packrtn(__builtin_amdgcn_rcpf(sv.x),
                                         __builtin_amdgcn_rcpf(sv.y));
    }
    if (tid < 32) zin2[0][zidx(tid)] = packrtn(xv.x, xv.y);
    if (tid >= 8 * w && tid < 8 * w + 8) zvec2[0][tid - 8 * w] = packrtn(xv.x, xv.y);
    __syncthreads();

    float* __restrict__ out_m = out;
    float* __restrict__ out_s = out + (size_t)SEQ * BATCH * HID;

    for (int t = 0; t < SEQ; ++t) {
        const int par = t & 1;
        const int np  = par ^ 1;
        const uint64_t want = (uint64_t)(t + 1);

        // ---- phase A: z_mid rows (64w+2g, +1), K split over 16 lanes ----
        {
            uint32_t zf[34];
            const uint32_t* zc = &zin2[par][c * 36];
            #pragma unroll
            for (int i = 0; i < 8; ++i) {
                uint4 v = *reinterpret_cast<const uint4*>(zc + 4 * i);
                zf[4 * i] = v.x; zf[4 * i + 1] = v.y; zf[4 * i + 2] = v.z; zf[4 * i + 3] = v.w;
            }
            { uint2 v = *reinterpret_cast<const uint2*>(zc + 32); zf[32] = v.x; zf[33] = v.y; }
            float a0 = 0.f, a1 = 0.f;
            #pragma unroll
            for (int i = 0; i < 34; ++i) {
                a0 = fdot2u(wA0[i], zf[i], a0);
                a1 = fdot2u(wA1[i], zf[i], a1);
            }
            a0 = red16(a0);
            a1 = red16(a1);
            if (c == 0)
                zvec2[par][8 + g] = packrtn(tanhf(a0 + bz0), tanhf(a1 + bz1));
        }
        __syncthreads();   // zvec z-quarter visible to phase B

        // ---- phase B: partial (s,m) for row h over this WG's 80-col slice ----
        float as = 0.f, am = 0.f;
        {
            uint32_t zg[40];
            #pragma unroll
            for (int i = 0; i < 10; ++i) {
                uint4 v = *reinterpret_cast<const uint4*>(&zvec2[par][4 * i]);
                zg[4 * i] = v.x; zg[4 * i + 1] = v.y; zg[4 * i + 2] = v.z; zg[4 * i + 3] = v.w;
            }
            #pragma unroll
            for (int i = 0; i < 40; ++i) {
                as = fdot2u(wS[i], zg[i], as);
                am = fdot2u(wM[i], zg[i], am);
            }
        }
        // publish stamped word {t+1, packed partials}; store issues in program
        // order before our polls and drains autonomously -> no barrier needed.
        __hip_atomic_store(&g_px[(((size_t)b * 2 + par) * NW + w) * HID + h],
                           (want << 32) | (uint64_t)packrtn(as, am),
                           __ATOMIC_RELAXED, __HIP_MEMORY_SCOPE_AGENT);

        // x prefetch for t+1: HBM latency hides under the poll
        if (tid < 32 && t + 1 < SEQ)
            xv = *reinterpret_cast<const float2*>(
                x + ((size_t)(t + 1) * BATCH + b) * IN_ + 2 * tid);

        // ---- poll 3 peers' stamped words CONCURRENTLY ----
        {
            const size_t base = ((size_t)b * 2 + par) * NW;
            const uint64_t* s0 = &g_px[(base + ((w + 1) & 3)) * HID + h];
            const uint64_t* s1 = &g_px[(base + ((w + 2) & 3)) * HID + h];
            const uint64_t* s2 = &g_px[(base + ((w + 3) & 3)) * HID + h];
            uint64_t p0 = 0, p1 = 0, p2 = 0;
            bool r0 = false, r1 = false, r2 = false;
            do {
                if (!r0) p0 = __hip_atomic_load(s0, __ATOMIC_RELAXED, __HIP_MEMORY_SCOPE_AGENT);
                if (!r1) p1 = __hip_atomic_load(s1, __ATOMIC_RELAXED, __HIP_MEMORY_SCOPE_AGENT);
                if (!r2) p2 = __hip_atomic_load(s2, __ATOMIC_RELAXED, __HIP_MEMORY_SCOPE_AGENT);
                r0 = (p0 >> 32) == want;
                r1 = (p1 >> 32) == want;
                r2 = (p2 >> 32) == want;
            } while (!(r0 && r1 && r2));
            h2t h0 = __builtin_bit_cast(h2t, (uint32_t)p0);
            h2t h1 = __builtin_bit_cast(h2t, (uint32_t)p1);
            h2t h2 = __builtin_bit_cast(h2t, (uint32_t)p2);
            as += (float)h0.x + (float)h1.x + (float)h2.x;
            am += (float)h0.y + (float)h1.y + (float)h2.y;
        }

        // ---- finish: state update for row h (redundant in all 4 WGs) ----
        const float sig  = 1.f / (1.f + expf(-(as + bsv)));
        const float ns   = sreg + sig;
        const float gate = sreg / ns;              // stop-grad: old_s / new_s
        const float nm   = gate * mreg + (1.f - gate) * tanhf(am + bmv);
        const float inv  = __builtin_amdgcn_rcpf(ns);
        sreg = ns; mreg = nm;

        // owner WG writes output for its h-quarter
        if ((h >> 7) == w) {
            const size_t o = ((size_t)t * BATCH + b) * HID + h;
            out_m[o] = nm;
            out_s[o] = ns;
        }

        // ---- stage zin[np](t+1) + zvec[np] x-slice (DPP pair swap) ----
        const float nm_n  = dpp_get<0xB1>(nm);     // neighbor lane^1 value
        const float inv_n = dpp_get<0xB1>(inv);
        if ((tid & 1) == 0) {
            zin2[np][zidx(32 + (tid >> 1))]  = packrtn(nm, nm_n);
            zin2[np][zidx(288 + (tid >> 1))] = packrtn(inv, inv_n);
        }
        if (t + 1 < SEQ) {
            if (tid < 32) zin2[np][zidx(tid)] = packrtn(xv.x, xv.y);
            if (tid >= 8 * w && tid < 8 * w + 8)
                zvec2[np][tid - 8 * w] = packrtn(xv.x, xv.y);
        }
        __syncthreads();   // staging stable before next phase A
    }
}

extern "C" void kernel_launch(void* const* d_in, const int* in_sizes, int n_in,
                              void* d_out, int out_size, void* d_ws, size_t ws_size,
                              hipStream_t stream) {
    const float* x     = (const float*)d_in[0];
    const float* old_m = (const float*)d_in[1];
    const float* old_s = (const float*)d_in[2];
    const float* W_z   = (const float*)d_in[3];
    const float* b_z   = (const float*)d_in[4];
    const float* W_s   = (const float*)d_in[5];
    const float* b_s   = (const float*)d_in[6];
    const float* W_m   = (const float*)d_in[7];
    const float* b_m   = (const float*)d_in[8];

    metamu7_kernel<<<dim3(BATCH * NW), dim3(512), 0, stream>>>(
        x, old_m, old_s, W_z, b_z, W_s, b_s, W_m, b_m, (float*)d_out);
}

// Round 7
// 1148.074 us; speedup vs baseline: 1.4326x; 1.4326x over previous
//
#include <hip/hip_runtime.h>
#include <math.h>
#include <stdint.h>

#define SEQ    512
#define BATCH  64
#define IN_    64
#define HID    512
#define MID    256
#define CONCAT 1088
#define ZS     320
#define NW     4      // workgroups per batch
#define QZ     64     // MID/NW: z_mid rows per WG

typedef _Float16 h2t __attribute__((ext_vector_type(2)));

__device__ __forceinline__ float fdot2u(uint32_t a, uint32_t b, float c) {
    return __builtin_amdgcn_fdot2(__builtin_bit_cast(h2t, a),
                                  __builtin_bit_cast(h2t, b), c, false);
}
__device__ __forceinline__ uint32_t packrtn(float a, float b) {
    h2t h = { (_Float16)a, (_Float16)b };
    return __builtin_bit_cast(uint32_t, h);
}
template <int CTRL>
__device__ __forceinline__ float dpp_add(float v) {
    int o = __builtin_amdgcn_update_dpp(0, __builtin_bit_cast(int, v), CTRL, 0xF, 0xF, true);
    return v + __builtin_bit_cast(float, o);
}
template <int CTRL>
__device__ __forceinline__ float dpp_get(float v) {   // fetch lane-permuted value
    int o = __builtin_amdgcn_update_dpp(0, __builtin_bit_cast(int, v), CTRL, 0xF, 0xF, true);
    return __builtin_bit_cast(float, o);
}
__device__ __forceinline__ float red16(float v) {     // sum over 16-lane group
    v = dpp_add<0xB1>(v);   // quad_perm xor1
    v = dpp_add<0x4E>(v);   // quad_perm xor2
    v = dpp_add<0x124>(v);  // row_ror:4
    v = dpp_add<0x128>(v);  // row_ror:8
    return v;
}
// zin: 16 chunks x 34 u32, padded to 36 (16B-aligned chunk base)
__device__ __forceinline__ int zidx(int k) { return (k / 34) * 36 + (k % 34); }

// Stamped exchange buffer: [BATCH][2(parity)][NW][HID] u64 words.
// hi32 = step stamp (t+1), lo32 = packed fp16 (s-partial, m-partial).
// Atomic 8B word => data self-validating; relaxed atomics suffice. Never
// reset: first call sees zero stamps; replays may read the previous replay's
// final-step word, which is bit-identical (kernel is deterministic).
__device__ uint64_t g_px[(size_t)BATCH * 2 * NW * HID];

// 4 WGs per batch. WG w holds: W_z rows [64w,64w+64) (full K=1088), and
// W_s/W_m COLUMN slices {x cols 16w..16w+15} U {z cols 64+64w..64+64w+63}
// for ALL 512 rows (1 thread per h row -> no reduce). One stamped-word LLC
// exchange per step: store -> per-thread vmcnt(0) drain (store reaches
// coherence point BEFORE polls start) -> 3 concurrent peer polls with
// s_sleep backoff. State finishing redundant in all 4 WGs; double-buffered
// LDS staging -> 2 barriers/step.
__global__ __launch_bounds__(512, 1)
void metamu8_kernel(const float* __restrict__ x,      // [SEQ][BATCH][IN_]
                    const float* __restrict__ old_m,  // [BATCH][HID]
                    const float* __restrict__ old_s,  // [BATCH][HID]
                    const float* __restrict__ W_z,    // [MID][CONCAT]
                    const float* __restrict__ b_z,
                    const float* __restrict__ W_s,    // [HID][ZS]
                    const float* __restrict__ b_s,
                    const float* __restrict__ W_m,    // [HID][ZS]
                    const float* __restrict__ b_m,
                    float* __restrict__ out)
{
    const int bid = blockIdx.x;
    const int b   = bid & 63;      // batch
    const int w   = bid >> 6;      // quarter
    const int tid = threadIdx.x;
    const int h   = tid;           // phase-B / finish row (global h)

    __shared__ __align__(16) uint32_t zin2[2][16 * 36]; // [x|m|1/s] fp16 pairs
    __shared__ __align__(16) uint32_t zvec2[2][40];     // [x-slice(8)|z-quarter(32)]

    const int g = tid >> 4, c = tid & 15;               // phase A: row pair, K-chunk

    // ---- one-time: weights -> VGPRs (fp16 RTN) ----
    uint32_t wA0[34], wA1[34];
    {
        const float* p0 = W_z + (size_t)(QZ * w + 2 * g) * CONCAT + 68 * c;
        const float* p1 = p0 + CONCAT;
        #pragma unroll
        for (int i = 0; i < 34; ++i) {
            float2 a  = *reinterpret_cast<const float2*>(p0 + 2 * i);
            float2 bb = *reinterpret_cast<const float2*>(p1 + 2 * i);
            wA0[i] = packrtn(a.x, a.y);
            wA1[i] = packrtn(bb.x, bb.y);
        }
    }
    uint32_t wS[40], wM[40];
    {
        const float* ps = W_s + (size_t)h * ZS;
        const float* pm = W_m + (size_t)h * ZS;
        #pragma unroll
        for (int i = 0; i < 8; ++i) {   // x-col slice: cols 16w+2i
            float2 a  = *reinterpret_cast<const float2*>(ps + 16 * w + 2 * i);
            float2 bb = *reinterpret_cast<const float2*>(pm + 16 * w + 2 * i);
            wS[i] = packrtn(a.x, a.y);
            wM[i] = packrtn(bb.x, bb.y);
        }
        #pragma unroll
        for (int i = 0; i < 32; ++i) {  // z-col slice: cols 64+64w+2i
            float2 a  = *reinterpret_cast<const float2*>(ps + 64 + 64 * w + 2 * i);
            float2 bb = *reinterpret_cast<const float2*>(pm + 64 + 64 * w + 2 * i);
            wS[8 + i] = packrtn(a.x, a.y);
            wM[8 + i] = packrtn(bb.x, bb.y);
        }
    }
    const float bz0 = b_z[QZ * w + 2 * g], bz1 = b_z[QZ * w + 2 * g + 1];
    const float bsv = b_s[h], bmv = b_m[h];

    // ---- registers: full per-h state (redundant across the 4 WGs) ----
    float sreg = old_s[b * HID + h];
    float mreg = old_m[b * HID + h];

    // x prefetch: threads 0..31 hold float pair (2*tid, 2*tid+1)
    float2 xv = {0.f, 0.f};
    if (tid < 32) xv = *reinterpret_cast<const float2*>(x + (size_t)b * IN_ + 2 * tid);

    // ---- initial staging of zin[0](t=0) and zvec[0] x-slice ----
    if (tid < 256) {
        float2 mv = *reinterpret_cast<const float2*>(old_m + b * HID + 2 * tid);
        zin2[0][zidx(32 + tid)] = packrtn(mv.x, mv.y);
    } else {
        const int j = tid - 256;
        float2 sv = *reinterpret_cast<const float2*>(old_s + b * HID + 2 * j);
        zin2[0][zidx(288 + j)] = packrtn(__builtin_amdgcn_rcpf(sv.x),
                                         __builtin_amdgcn_rcpf(sv.y));
    }
    if (tid < 32) zin2[0][zidx(tid)] = packrtn(xv.x, xv.y);
    if (tid >= 8 * w && tid < 8 * w + 8) zvec2[0][tid - 8 * w] = packrtn(xv.x, xv.y);
    __syncthreads();

    float* __restrict__ out_m = out;
    float* __restrict__ out_s = out + (size_t)SEQ * BATCH * HID;

    for (int t = 0; t < SEQ; ++t) {
        const int par = t & 1;
        const int np  = par ^ 1;
        const uint64_t want = (uint64_t)(t + 1);

        // ---- phase A: z_mid rows (64w+2g, +1), K split over 16 lanes ----
        {
            uint32_t zf[34];
            const uint32_t* zc = &zin2[par][c * 36];
            #pragma unroll
            for (int i = 0; i < 8; ++i) {
                uint4 v = *reinterpret_cast<const uint4*>(zc + 4 * i);
                zf[4 * i] = v.x; zf[4 * i + 1] = v.y; zf[4 * i + 2] = v.z; zf[4 * i + 3] = v.w;
            }
            { uint2 v = *reinterpret_cast<const uint2*>(zc + 32); zf[32] = v.x; zf[33] = v.y; }
            float a0 = 0.f, a1 = 0.f;
            #pragma unroll
            for (int i = 0; i < 34; ++i) {
                a0 = fdot2u(wA0[i], zf[i], a0);
                a1 = fdot2u(wA1[i], zf[i], a1);
            }
            a0 = red16(a0);
            a1 = red16(a1);
            if (c == 0)
                zvec2[par][8 + g] = packrtn(tanhf(a0 + bz0), tanhf(a1 + bz1));
        }
        __syncthreads();   // zvec z-quarter visible to phase B

        // ---- phase B: partial (s,m) for row h over this WG's 80-col slice ----
        float as = 0.f, am = 0.f;
        {
            uint32_t zg[40];
            #pragma unroll
            for (int i = 0; i < 10; ++i) {
                uint4 v = *reinterpret_cast<const uint4*>(&zvec2[par][4 * i]);
                zg[4 * i] = v.x; zg[4 * i + 1] = v.y; zg[4 * i + 2] = v.z; zg[4 * i + 3] = v.w;
            }
            #pragma unroll
            for (int i = 0; i < 40; ++i) {
                as = fdot2u(wS[i], zg[i], as);
                am = fdot2u(wM[i], zg[i], am);
            }
        }
        // publish stamped word {t+1, packed partials}, then drain it to the
        // coherence point BEFORE issuing any poll loads (per-thread, no WG
        // barrier). This keeps our store off the critical path of peers.
        __hip_atomic_store(&g_px[(((size_t)b * 2 + par) * NW + w) * HID + h],
                           (want << 32) | (uint64_t)packrtn(as, am),
                           __ATOMIC_RELAXED, __HIP_MEMORY_SCOPE_AGENT);
        asm volatile("s_waitcnt vmcnt(0)" ::: "memory");

        // x prefetch for t+1: HBM latency hides under the poll
        if (tid < 32 && t + 1 < SEQ)
            xv = *reinterpret_cast<const float2*>(
                x + ((size_t)(t + 1) * BATCH + b) * IN_ + 2 * tid);

        // ---- poll 3 peers' stamped words CONCURRENTLY (sleep on retry) ----
        {
            const size_t base = ((size_t)b * 2 + par) * NW;
            const uint64_t* s0 = &g_px[(base + ((w + 1) & 3)) * HID + h];
            const uint64_t* s1 = &g_px[(base + ((w + 2) & 3)) * HID + h];
            const uint64_t* s2 = &g_px[(base + ((w + 3) & 3)) * HID + h];
            uint64_t p0 = __hip_atomic_load(s0, __ATOMIC_RELAXED, __HIP_MEMORY_SCOPE_AGENT);
            uint64_t p1 = __hip_atomic_load(s1, __ATOMIC_RELAXED, __HIP_MEMORY_SCOPE_AGENT);
            uint64_t p2 = __hip_atomic_load(s2, __ATOMIC_RELAXED, __HIP_MEMORY_SCOPE_AGENT);
            bool r0 = (p0 >> 32) == want;
            bool r1 = (p1 >> 32) == want;
            bool r2 = (p2 >> 32) == want;
            while (!(r0 && r1 && r2)) {
                __builtin_amdgcn_s_sleep(1);   // back off: don't starve stores
                if (!r0) { p0 = __hip_atomic_load(s0, __ATOMIC_RELAXED, __HIP_MEMORY_SCOPE_AGENT); }
                if (!r1) { p1 = __hip_atomic_load(s1, __ATOMIC_RELAXED, __HIP_MEMORY_SCOPE_AGENT); }
                if (!r2) { p2 = __hip_atomic_load(s2, __ATOMIC_RELAXED, __HIP_MEMORY_SCOPE_AGENT); }
                r0 = (p0 >> 32) == want;
                r1 = (p1 >> 32) == want;
                r2 = (p2 >> 32) == want;
            }
            h2t h0 = __builtin_bit_cast(h2t, (uint32_t)p0);
            h2t h1 = __builtin_bit_cast(h2t, (uint32_t)p1);
            h2t h2 = __builtin_bit_cast(h2t, (uint32_t)p2);
            as += (float)h0.x + (float)h1.x + (float)h2.x;
            am += (float)h0.y + (float)h1.y + (float)h2.y;
        }

        // ---- finish: state update for row h (redundant in all 4 WGs) ----
        const float sig  = 1.f / (1.f + expf(-(as + bsv)));
        const float ns   = sreg + sig;
        const float gate = sreg / ns;              // stop-grad: old_s / new_s
        const float nm   = gate * mreg + (1.f - gate) * tanhf(am + bmv);
        const float inv  = __builtin_amdgcn_rcpf(ns);
        sreg = ns; mreg = nm;

        // owner WG writes output for its h-quarter
        if ((h >> 7) == w) {
            const size_t o = ((size_t)t * BATCH + b) * HID + h;
            out_m[o] = nm;
            out_s[o] = ns;
        }

        // ---- stage zin[np](t+1) + zvec[np] x-slice (DPP pair swap) ----
        const float nm_n  = dpp_get<0xB1>(nm);     // neighbor lane^1 value
        const float inv_n = dpp_get<0xB1>(inv);
        if ((tid & 1) == 0) {
            zin2[np][zidx(32 + (tid >> 1))]  = packrtn(nm, nm_n);
            zin2[np][zidx(288 + (tid >> 1))] = packrtn(inv, inv_n);
        }
        if (t + 1 < SEQ) {
            if (tid < 32) zin2[np][zidx(tid)] = packrtn(xv.x, xv.y);
            if (tid >= 8 * w && tid < 8 * w + 8)
                zvec2[np][tid - 8 * w] = packrtn(xv.x, xv.y);
        }
        __syncthreads();   // staging stable before next phase A
    }
}

extern "C" void kernel_launch(void* const* d_in, const int* in_sizes, int n_in,
                              void* d_out, int out_size, void* d_ws, size_t ws_size,
                              hipStream_t stream) {
    const float* x     = (const float*)d_in[0];
    const float* old_m = (const float*)d_in[1];
    const float* old_s = (const float*)d_in[2];
    const float* W_z   = (const float*)d_in[3];
    const float* b_z   = (const float*)d_in[4];
    const float* W_s   = (const float*)d_in[5];
    const float* b_s   = (const float*)d_in[6];
    const float* W_m   = (const float*)d_in[7];
    const float* b_m   = (const float*)d_in[8];

    metamu8_kernel<<<dim3(BATCH * NW), dim3(512), 0, stream>>>(
        x, old_m, old_s, W_z, b_z, W_s, b_s, W_m, b_m, (float*)d_out);
}

// Round 8
// 1041.383 us; speedup vs baseline: 1.5794x; 1.1025x over previous
//
#include <hip/hip_runtime.h>
#include <math.h>
#include <stdint.h>

#define SEQ    512
#define BATCH  64
#define IN_    64
#define HID    512
#define MID    256
#define CONCAT 1088
#define ZS     320
#define NW     4      // workgroups per batch
#define QZ     64     // MID/NW: z_mid rows per WG
#define L2E    1.4426950408889634f

typedef _Float16 h2t __attribute__((ext_vector_type(2)));

__device__ __forceinline__ float fdot2u(uint32_t a, uint32_t b, float c) {
    return __builtin_amdgcn_fdot2(__builtin_bit_cast(h2t, a),
                                  __builtin_bit_cast(h2t, b), c, false);
}
__device__ __forceinline__ uint32_t packrtn(float a, float b) {
    h2t h = { (_Float16)a, (_Float16)b };
    return __builtin_bit_cast(uint32_t, h);
}
template <int CTRL>
__device__ __forceinline__ float dpp_add(float v) {
    int o = __builtin_amdgcn_update_dpp(0, __builtin_bit_cast(int, v), CTRL, 0xF, 0xF, true);
    return v + __builtin_bit_cast(float, o);
}
template <int CTRL>
__device__ __forceinline__ float dpp_get(float v) {   // fetch lane-permuted value
    int o = __builtin_amdgcn_update_dpp(0, __builtin_bit_cast(int, v), CTRL, 0xF, 0xF, true);
    return __builtin_bit_cast(float, o);
}
__device__ __forceinline__ float red16(float v) {     // sum over 16-lane DPP row
    v = dpp_add<0xB1>(v);   // quad_perm xor1
    v = dpp_add<0x4E>(v);   // quad_perm xor2
    v = dpp_add<0x124>(v);  // row_ror:4
    v = dpp_add<0x128>(v);  // row_ror:8
    return v;
}
__device__ __forceinline__ float sw_add16(float v) {  // += lane^16 value
    int o = __builtin_amdgcn_ds_swizzle(__builtin_bit_cast(int, v), 0x401F);
    return v + __builtin_bit_cast(float, o);
}
// fast transcendentals: v_exp_f32 (2^x) + v_rcp_f32; ~1 ulp, saturation-safe
__device__ __forceinline__ float fexp2(float x) {
    float r;
    asm("v_exp_f32 %0, %1" : "=v"(r) : "v"(x));
    return r;
}
__device__ __forceinline__ float frcp(float x) { return __builtin_amdgcn_rcpf(x); }
__device__ __forceinline__ float fsigmoid(float x) {   // 1/(1+e^-x)
    return frcp(1.f + fexp2(-x * L2E));
}
__device__ __forceinline__ float ftanh(float x) {      // 1 - 2/(e^2x+1)
    return 1.f - 2.f * frcp(fexp2(x * (2.f * L2E)) + 1.f);
}
// zin: 32 chunks x 17 u32, padded to 20 (80B, 16B-aligned chunk base)
__device__ __forceinline__ int zidx(int k) { return (k / 17) * 20 + (k % 17); }

// Stamped exchange buffer: [BATCH][2(parity)][NW][HID] u64 words.
// hi32 = step stamp (t+1), lo32 = packed fp16 (s-partial, m-partial).
// Atomic 8B word => data self-validating; relaxed atomics suffice. Never
// reset: first call sees zero stamps; replays may read the previous replay's
// final-step word, which is bit-identical (kernel is deterministic).
__device__ uint64_t g_px[(size_t)BATCH * 2 * NW * HID];

// 4 WGs per batch. WG w holds: W_z rows [64w,64w+64) (full K=1088; thread
// (g2,c2) = rows 4g2..4g2+3 x K-chunk c2 of 34 elems), and W_s/W_m column
// slices for rows (tid&~1, tid|1) x col-half (tid&1) of the WG's 80-col
// slice. One stamped-word LLC exchange per step: store -> per-thread
// vmcnt(0) drain -> 3 concurrent peer polls with s_sleep backoff. State
// finishing redundant in all 4 WGs; double-buffered staging, 2 barriers.
__global__ __launch_bounds__(512, 1)
void metamu9_kernel(const float* __restrict__ x,      // [SEQ][BATCH][IN_]
                    const float* __restrict__ old_m,  // [BATCH][HID]
                    const float* __restrict__ old_s,  // [BATCH][HID]
                    const float* __restrict__ W_z,    // [MID][CONCAT]
                    const float* __restrict__ b_z,
                    const float* __restrict__ W_s,    // [HID][ZS]
                    const float* __restrict__ b_s,
                    const float* __restrict__ W_m,    // [HID][ZS]
                    const float* __restrict__ b_m,
                    float* __restrict__ out)
{
    const int bid = blockIdx.x;
    const int b   = bid & 63;      // batch
    const int w   = bid >> 6;      // quarter
    const int tid = threadIdx.x;
    const int h   = tid;           // finish/px row (same mapping as round 7)

    __shared__ __align__(16) uint32_t zin2[2][32 * 20]; // [x|m|1/s] fp16 pairs
    __shared__ __align__(16) uint32_t zvec2[2][40];     // [x-slice(8)|z-quarter(32)]

    const int g2 = tid >> 5, c2 = tid & 31;   // phase A: 4-row group, K-chunk
    const int l  = tid & 1;                    // phase B: column-half

    // ---- one-time: weights -> VGPRs (fp16 RTN) ----
    uint32_t wA[4][17];
    #pragma unroll
    for (int r = 0; r < 4; ++r) {
        const float* p = W_z + (size_t)(QZ * w + 4 * g2 + r) * CONCAT + 34 * c2;
        #pragma unroll
        for (int i = 0; i < 17; ++i) {
            float2 a = *reinterpret_cast<const float2*>(p + 2 * i);
            wA[r][i] = packrtn(a.x, a.y);
        }
    }
    // phase-B: rows h0=tid&~1, h1=tid|1; col-half l of {x 16w..+16} U {z 64w..+64}
    uint32_t wS0[20], wM0[20], wS1[20], wM1[20];
    {
        const int h0 = tid & ~1, h1 = tid | 1;
        const float* ps0 = W_s + (size_t)h0 * ZS;
        const float* pm0 = W_m + (size_t)h0 * ZS;
        const float* ps1 = W_s + (size_t)h1 * ZS;
        const float* pm1 = W_m + (size_t)h1 * ZS;
        #pragma unroll
        for (int i = 0; i < 4; ++i) {   // x cols: 16w + 8l + 2i
            const int o = 16 * w + 8 * l + 2 * i;
            float2 a0 = *reinterpret_cast<const float2*>(ps0 + o);
            float2 b0 = *reinterpret_cast<const float2*>(pm0 + o);
            float2 a1 = *reinterpret_cast<const float2*>(ps1 + o);
            float2 b1 = *reinterpret_cast<const float2*>(pm1 + o);
            wS0[i] = packrtn(a0.x, a0.y); wM0[i] = packrtn(b0.x, b0.y);
            wS1[i] = packrtn(a1.x, a1.y); wM1[i] = packrtn(b1.x, b1.y);
        }
        #pragma unroll
        for (int i = 0; i < 16; ++i) {  // z cols: 64 + 64w + 32l + 2i
            const int o = 64 + 64 * w + 32 * l + 2 * i;
            float2 a0 = *reinterpret_cast<const float2*>(ps0 + o);
            float2 b0 = *reinterpret_cast<const float2*>(pm0 + o);
            float2 a1 = *reinterpret_cast<const float2*>(ps1 + o);
            float2 b1 = *reinterpret_cast<const float2*>(pm1 + o);
            wS0[4 + i] = packrtn(a0.x, a0.y); wM0[4 + i] = packrtn(b0.x, b0.y);
            wS1[4 + i] = packrtn(a1.x, a1.y); wM1[4 + i] = packrtn(b1.x, b1.y);
        }
    }
    float bz[4];
    #pragma unroll
    for (int r = 0; r < 4; ++r) bz[r] = b_z[QZ * w + 4 * g2 + r];
    const float bsv = b_s[h], bmv = b_m[h];

    // ---- registers: full per-h state (redundant across the 4 WGs) ----
    float sreg = old_s[b * HID + h];
    float mreg = old_m[b * HID + h];

    // x prefetch: threads 0..31 hold float pair (2*tid, 2*tid+1)
    float2 xv = {0.f, 0.f};
    if (tid < 32) xv = *reinterpret_cast<const float2*>(x + (size_t)b * IN_ + 2 * tid);

    // ---- initial staging of zin[0](t=0) and zvec[0] x-slice ----
    if (tid < 256) {
        float2 mv = *reinterpret_cast<const float2*>(old_m + b * HID + 2 * tid);
        zin2[0][zidx(32 + tid)] = packrtn(mv.x, mv.y);
    } else {
        const int j = tid - 256;
        float2 sv = *reinterpret_cast<const float2*>(old_s + b * HID + 2 * j);
        zin2[0][zidx(288 + j)] = packrtn(frcp(sv.x), frcp(sv.y));
    }
    if (tid < 32) zin2[0][zidx(tid)] = packrtn(xv.x, xv.y);
    if (tid >= 8 * w && tid < 8 * w + 8) zvec2[0][tid - 8 * w] = packrtn(xv.x, xv.y);
    __syncthreads();

    float* __restrict__ out_m = out;
    float* __restrict__ out_s = out + (size_t)SEQ * BATCH * HID;

    for (int t = 0; t < SEQ; ++t) {
        const int par = t & 1;
        const int np  = par ^ 1;
        const uint64_t want = (uint64_t)(t + 1);

        // ---- phase A: z_mid rows 4g2..4g2+3, K split over 32 lanes ----
        {
            uint32_t zf[17];
            const uint32_t* zc = &zin2[par][c2 * 20];
            #pragma unroll
            for (int i = 0; i < 4; ++i) {
                uint4 v = *reinterpret_cast<const uint4*>(zc + 4 * i);
                zf[4 * i] = v.x; zf[4 * i + 1] = v.y; zf[4 * i + 2] = v.z; zf[4 * i + 3] = v.w;
            }
            zf[16] = zc[16];
            float a0 = 0.f, a1 = 0.f, a2 = 0.f, a3 = 0.f;
            #pragma unroll
            for (int i = 0; i < 17; ++i) {
                a0 = fdot2u(wA[0][i], zf[i], a0);
                a1 = fdot2u(wA[1][i], zf[i], a1);
                a2 = fdot2u(wA[2][i], zf[i], a2);
                a3 = fdot2u(wA[3][i], zf[i], a3);
            }
            a0 = sw_add16(red16(a0));
            a1 = sw_add16(red16(a1));
            a2 = sw_add16(red16(a2));
            a3 = sw_add16(red16(a3));
            if (c2 == 0) {
                zvec2[par][8 + 2 * g2]     = packrtn(ftanh(a0 + bz[0]), ftanh(a1 + bz[1]));
                zvec2[par][8 + 2 * g2 + 1] = packrtn(ftanh(a2 + bz[2]), ftanh(a3 + bz[3]));
            }
        }
        __syncthreads();   // zvec z-quarter visible to phase B

        // ---- phase B: rows (tid&~1, tid|1) x col-half l; xor1 -> full sums ----
        float as, am;
        {
            uint32_t zg[20];
            {
                uint4 v = *reinterpret_cast<const uint4*>(&zvec2[par][4 * l]);
                zg[0] = v.x; zg[1] = v.y; zg[2] = v.z; zg[3] = v.w;
            }
            const uint32_t* zc2 = &zvec2[par][8 + 16 * l];
            #pragma unroll
            for (int i = 0; i < 4; ++i) {
                uint4 v = *reinterpret_cast<const uint4*>(zc2 + 4 * i);
                zg[4 + 4 * i] = v.x; zg[5 + 4 * i] = v.y; zg[6 + 4 * i] = v.z; zg[7 + 4 * i] = v.w;
            }
            float as0 = 0.f, am0 = 0.f, as1 = 0.f, am1 = 0.f;
            #pragma unroll
            for (int i = 0; i < 20; ++i) {
                as0 = fdot2u(wS0[i], zg[i], as0);
                am0 = fdot2u(wM0[i], zg[i], am0);
                as1 = fdot2u(wS1[i], zg[i], as1);
                am1 = fdot2u(wM1[i], zg[i], am1);
            }
            as0 = dpp_add<0xB1>(as0);   // + other column-half (lane^1)
            am0 = dpp_add<0xB1>(am0);
            as1 = dpp_add<0xB1>(as1);
            am1 = dpp_add<0xB1>(am1);
            as = l ? as1 : as0;          // full per-WG partial for row h = tid
            am = l ? am1 : am0;
        }
        // publish stamped word {t+1, packed partials}, then drain it to the
        // coherence point BEFORE issuing any poll loads (per-thread).
        __hip_atomic_store(&g_px[(((size_t)b * 2 + par) * NW + w) * HID + h],
                           (want << 32) | (uint64_t)packrtn(as, am),
                           __ATOMIC_RELAXED, __HIP_MEMORY_SCOPE_AGENT);
        asm volatile("s_waitcnt vmcnt(0)" ::: "memory");

        // x prefetch for t+1: HBM latency hides under the poll
        if (tid < 32 && t + 1 < SEQ)
            xv = *reinterpret_cast<const float2*>(
                x + ((size_t)(t + 1) * BATCH + b) * IN_ + 2 * tid);

        // ---- poll 3 peers' stamped words CONCURRENTLY (sleep on retry) ----
        {
            const size_t base = ((size_t)b * 2 + par) * NW;
            const uint64_t* s0 = &g_px[(base + ((w + 1) & 3)) * HID + h];
            const uint64_t* s1 = &g_px[(base + ((w + 2) & 3)) * HID + h];
            const uint64_t* s2 = &g_px[(base + ((w + 3) & 3)) * HID + h];
            uint64_t p0 = __hip_atomic_load(s0, __ATOMIC_RELAXED, __HIP_MEMORY_SCOPE_AGENT);
            uint64_t p1 = __hip_atomic_load(s1, __ATOMIC_RELAXED, __HIP_MEMORY_SCOPE_AGENT);
            uint64_t p2 = __hip_atomic_load(s2, __ATOMIC_RELAXED, __HIP_MEMORY_SCOPE_AGENT);
            bool r0 = (p0 >> 32) == want;
            bool r1 = (p1 >> 32) == want;
            bool r2 = (p2 >> 32) == want;
            while (!(r0 && r1 && r2)) {
                __builtin_amdgcn_s_sleep(1);   // back off: don't starve stores
                if (!r0) { p0 = __hip_atomic_load(s0, __ATOMIC_RELAXED, __HIP_MEMORY_SCOPE_AGENT); }
                if (!r1) { p1 = __hip_atomic_load(s1, __ATOMIC_RELAXED, __HIP_MEMORY_SCOPE_AGENT); }
                if (!r2) { p2 = __hip_atomic_load(s2, __ATOMIC_RELAXED, __HIP_MEMORY_SCOPE_AGENT); }
                r0 = (p0 >> 32) == want;
                r1 = (p1 >> 32) == want;
                r2 = (p2 >> 32) == want;
            }
            h2t h0 = __builtin_bit_cast(h2t, (uint32_t)p0);
            h2t h1 = __builtin_bit_cast(h2t, (uint32_t)p1);
            h2t h2 = __builtin_bit_cast(h2t, (uint32_t)p2);
            as += (float)h0.x + (float)h1.x + (float)h2.x;
            am += (float)h0.y + (float)h1.y + (float)h2.y;
        }

        // ---- finish: state update for row h (redundant in all 4 WGs) ----
        const float sig  = fsigmoid(as + bsv);
        const float ns   = sreg + sig;
        const float inv  = frcp(ns);
        const float gate = sreg * inv;             // stop-grad: old_s / new_s
        const float nm   = gate * mreg + (1.f - gate) * ftanh(am + bmv);
        sreg = ns; mreg = nm;

        // owner WG writes output for its h-quarter
        if ((h >> 7) == w) {
            const size_t o = ((size_t)t * BATCH + b) * HID + h;
            out_m[o] = nm;
            out_s[o] = ns;
        }

        // ---- stage zin[np](t+1) + zvec[np] x-slice (DPP pair swap) ----
        const float nm_n  = dpp_get<0xB1>(nm);     // neighbor lane^1 value
        const float inv_n = dpp_get<0xB1>(inv);
        if ((tid & 1) == 0) {
            zin2[np][zidx(32 + (tid >> 1))]  = packrtn(nm, nm_n);
            zin2[np][zidx(288 + (tid >> 1))] = packrtn(inv, inv_n);
        }
        if (t + 1 < SEQ) {
            if (tid < 32) zin2[np][zidx(tid)] = packrtn(xv.x, xv.y);
            if (tid >= 8 * w && tid < 8 * w + 8)
                zvec2[np][tid - 8 * w] = packrtn(xv.x, xv.y);
        }
        __syncthreads();   // staging stable before next phase A
    }
}

extern "C" void kernel_launch(void* const* d_in, const int* in_sizes, int n_in,
                              void* d_out, int out_size, void* d_ws, size_t ws_size,
                              hipStream_t stream) {
    const float* x     = (const float*)d_in[0];
    const float* old_m = (const float*)d_in[1];
    const float* old_s = (const float*)d_in[2];
    const float* W_z   = (const float*)d_in[3];
    const float* b_z   = (const float*)d_in[4];
    const float* W_s   = (const float*)d_in[5];
    const float* b_s   = (const float*)d_in[6];
    const float* W_m   = (const float*)d_in[7];
    const float* b_m   = (const float*)d_in[8];

    metamu9_kernel<<<dim3(BATCH * NW), dim3(512), 0, stream>>>(
        x, old_m, old_s, W_z, b_z, W_s, b_s, W_m, b_m, (float*)d_out);
}